// Round 2
// baseline (530.697 us; speedup 1.0000x reference)
//
#include <hip/hip_runtime.h>
#include <math.h>

#define HDIM 768      // H (hidden) — instance-fixed
#define CHUNK 8       // rows per score/accumulate step
#define LMAX 512      // mask row staged in LDS

// ---------------- kernel 0: input-width detection ----------------
// flags[0] != 0  -> attention_mask buffer is int32-layout (else int64)
// flags[1] != 0  -> sample_map buffer is int32-layout (else int64)
// Scans only the first `words` 32-bit words (guaranteed in-bounds for either
// layout) and ORs the odd words: int64 {0,1}-valued data has all-zero hi-words.
__global__ __launch_bounds__(256) void detect_flags(const unsigned* __restrict__ mask_w,
                                                    const unsigned* __restrict__ smap_w,
                                                    unsigned* __restrict__ flags,
                                                    int mask_words, int smap_words) {
  const int gtid = blockIdx.x * blockDim.x + threadIdx.x;
  const int gsz = gridDim.x * blockDim.x;
  unsigned acc = 0;
  for (int i = gtid; i < mask_words / 2; i += gsz) acc |= mask_w[2 * i + 1];
  if (acc) atomicOr(&flags[0], 1u);
  unsigned acc2 = 0;
  for (int i = gtid; i < smap_words / 2; i += gsz) acc2 |= smap_w[2 * i + 1];
  if (acc2) atomicOr(&flags[1], 1u);
}

// ---------------- kernel 1: mean over L ----------------
__global__ __launch_bounds__(192) void mean_kernel(const float* __restrict__ hs,
                                                   float* __restrict__ meanb, int L) {
  const int n = blockIdx.x;
  const int t = threadIdx.x;  // 0..191
  const float4* row = reinterpret_cast<const float4*>(hs) + (size_t)n * L * (HDIM / 4);
  float ax = 0.f, ay = 0.f, az = 0.f, aw = 0.f;
  int l = 0;
  for (; l + 8 <= L; l += 8) {
    float4 u[8];
#pragma unroll
    for (int i = 0; i < 8; ++i) u[i] = row[(size_t)(l + i) * (HDIM / 4) + t];
#pragma unroll
    for (int i = 0; i < 8; ++i) { ax += u[i].x; ay += u[i].y; az += u[i].z; aw += u[i].w; }
  }
  for (; l < L; ++l) {
    float4 u = row[(size_t)l * (HDIM / 4) + t];
    ax += u.x; ay += u.y; az += u.z; aw += u.w;
  }
  const float inv = 1.0f / (float)L;
  float4 o; o.x = ax * inv; o.y = ay * inv; o.z = az * inv; o.w = aw * inv;
  reinterpret_cast<float4*>(meanb + (size_t)n * HDIM)[t] = o;
}

// ---------------- kernel 2: C[M,Nn] = A[M,K] * B[Nn,K]^T + bias ----------------
__global__ __launch_bounds__(512) void gemm_bt(const float* __restrict__ A,
                                               const float* __restrict__ B,
                                               const float* __restrict__ bias,
                                               float* __restrict__ C,
                                               int M, int Nn, int K) {
  __shared__ float As[64][17];
  __shared__ float Bs[64][17];
  const int m0 = blockIdx.x * 64, n0 = blockIdx.y * 64;
  const int idx = threadIdx.x;
  const int lc = idx & 15, lr = idx >> 4;
  const int tc = idx & 15, tr = idx >> 4;
  float c[2][4] = {{0.f,0.f,0.f,0.f},{0.f,0.f,0.f,0.f}};
  for (int k0 = 0; k0 < K; k0 += 16) {
    __syncthreads();
    As[lr][lc]      = A[(size_t)(m0 + lr) * K + k0 + lc];
    As[lr + 32][lc] = A[(size_t)(m0 + lr + 32) * K + k0 + lc];
    Bs[lr][lc]      = B[(size_t)(n0 + lr) * K + k0 + lc];
    Bs[lr + 32][lc] = B[(size_t)(n0 + lr + 32) * K + k0 + lc];
    __syncthreads();
#pragma unroll
    for (int k = 0; k < 16; ++k) {
      const float a0 = As[tr * 2][k], a1 = As[tr * 2 + 1][k];
      const float b0 = Bs[tc * 4][k], b1 = Bs[tc * 4 + 1][k];
      const float b2 = Bs[tc * 4 + 2][k], b3 = Bs[tc * 4 + 3][k];
      c[0][0] += a0 * b0; c[0][1] += a0 * b1; c[0][2] += a0 * b2; c[0][3] += a0 * b3;
      c[1][0] += a1 * b0; c[1][1] += a1 * b1; c[1][2] += a1 * b2; c[1][3] += a1 * b3;
    }
  }
#pragma unroll
  for (int j = 0; j < 4; ++j) {
    const float bv = bias ? bias[n0 + tc * 4 + j] : 0.f;
    C[(size_t)(m0 + tr * 2) * Nn + n0 + tc * 4 + j]     = c[0][j] + bv;
    C[(size_t)(m0 + tr * 2 + 1) * Nn + n0 + tc * 4 + j] = c[1][j] + bv;
  }
}

// ---------------- kernel 3: C[M,Nn] = A[M,K] * B[K,Nn] ----------------
__global__ __launch_bounds__(512) void gemm_bn(const float* __restrict__ A,
                                               const float* __restrict__ B,
                                               float* __restrict__ C,
                                               int M, int Nn, int K) {
  __shared__ float As[64][17];
  __shared__ float Bs[16][65];
  const int m0 = blockIdx.x * 64, n0 = blockIdx.y * 64;
  const int idx = threadIdx.x;
  const int lc = idx & 15, lr = idx >> 4;
  const int bc = idx & 63, br = idx >> 6;
  const int tc = idx & 15, tr = idx >> 4;
  float c[2][4] = {{0.f,0.f,0.f,0.f},{0.f,0.f,0.f,0.f}};
  for (int k0 = 0; k0 < K; k0 += 16) {
    __syncthreads();
    As[lr][lc]      = A[(size_t)(m0 + lr) * K + k0 + lc];
    As[lr + 32][lc] = A[(size_t)(m0 + lr + 32) * K + k0 + lc];
    Bs[br][bc]      = B[(size_t)(k0 + br) * Nn + n0 + bc];
    Bs[br + 8][bc]  = B[(size_t)(k0 + br + 8) * Nn + n0 + bc];
    __syncthreads();
#pragma unroll
    for (int k = 0; k < 16; ++k) {
      const float a0 = As[tr * 2][k], a1 = As[tr * 2 + 1][k];
      const float b0 = Bs[k][tc * 4], b1 = Bs[k][tc * 4 + 1];
      const float b2 = Bs[k][tc * 4 + 2], b3 = Bs[k][tc * 4 + 3];
      c[0][0] += a0 * b0; c[0][1] += a0 * b1; c[0][2] += a0 * b2; c[0][3] += a0 * b3;
      c[1][0] += a1 * b0; c[1][1] += a1 * b1; c[1][2] += a1 * b2; c[1][3] += a1 * b3;
    }
  }
#pragma unroll
  for (int j = 0; j < 4; ++j) {
    C[(size_t)(m0 + tr * 2) * Nn + n0 + tc * 4 + j]     = c[0][j];
    C[(size_t)(m0 + tr * 2 + 1) * Nn + n0 + tc * 4 + j] = c[1][j];
  }
}

// ---------------- kernel 4: fused scores + online softmax + weighted pool ----------------
// Direct global reads (no LDS staging of hs): score pass fetches the 24 KB
// chunk (HBM), accumulate pass re-reads it from L1/L2.
__global__ __launch_bounds__(256) void attnpool(const float* __restrict__ hs,
                                                const unsigned* __restrict__ mask_w,
                                                const float* __restrict__ v,
                                                const unsigned* __restrict__ flags,
                                                float* __restrict__ pooled, int L) {
  __shared__ int   mrow[LMAX];
  __shared__ float sc[CHUNK];
  const int n = blockIdx.x;
  const int tid = threadIdx.x;
  const int w = tid >> 6, lane = tid & 63;

  // mask row -> LDS (width-robust decode)
  const int mask_is_i32 = (flags[0] != 0);
  for (int t = tid; t < L; t += 256) {
    const size_t idx = (size_t)n * L + t;
    mrow[t] = (int)(mask_is_i32 ? mask_w[idx] : mask_w[2 * idx]);
  }

  const float4* v4 = reinterpret_cast<const float4*>(v + (size_t)n * HDIM);
  const float4 vf0 = v4[lane], vf1 = v4[64 + lane], vf2 = v4[128 + lane];
  const float4* hs4 = reinterpret_cast<const float4*>(hs);
  const float scale = 1.0f / sqrtf((float)HDIM);

  float m = -1e9f, ssum = 0.f, a0 = 0.f, a1 = 0.f, a2 = 0.f;
  __syncthreads();  // mrow staged

  const int nch = L / CHUNK;
  for (int c = 0; c < nch; ++c) {
    // ---- score pass: wave w computes rows 2w, 2w+1 of this chunk ----
#pragma unroll
    for (int q = 0; q < 2; ++q) {
      const int r = 2 * w + q;
      const float4* rp = hs4 + ((size_t)n * L + c * CHUNK + r) * (HDIM / 4);
      const float4 x0 = rp[lane], x1 = rp[64 + lane], x2 = rp[128 + lane];
      float p = x0.x * vf0.x + x0.y * vf0.y + x0.z * vf0.z + x0.w * vf0.w
              + x1.x * vf1.x + x1.y * vf1.y + x1.z * vf1.z + x1.w * vf1.w
              + x2.x * vf2.x + x2.y * vf2.y + x2.z * vf2.z + x2.w * vf2.w;
#pragma unroll
      for (int off = 32; off > 0; off >>= 1) p += __shfl_xor(p, off, 64);
      float s = p * scale;
      if (mrow[c * CHUNK + r] == 0) s = -1e9f;
      if (lane == 0) sc[r] = s;
    }
    __syncthreads();  // scores visible

    // ---- online softmax update + weighted accumulation ----
    float pp[CHUNK];
    float mc = -3e38f;
#pragma unroll
    for (int r = 0; r < CHUNK; ++r) { pp[r] = sc[r]; mc = fmaxf(mc, pp[r]); }
    const float mn = fmaxf(m, mc);
    const float f = __expf(m - mn);
    float psum = 0.f;
#pragma unroll
    for (int r = 0; r < CHUNK; ++r) { pp[r] = __expf(pp[r] - mn); psum += pp[r]; }
    ssum = ssum * f + psum;
    a0 *= f; a1 *= f; a2 *= f;
    const float* rowbase = hs + ((size_t)n * L + c * CHUNK) * HDIM;
#pragma unroll
    for (int r = 0; r < CHUNK; ++r) {
      a0 += pp[r] * rowbase[r * HDIM + tid];
      a1 += pp[r] * rowbase[r * HDIM + 256 + tid];
      a2 += pp[r] * rowbase[r * HDIM + 512 + tid];
    }
    m = mn;
    __syncthreads();  // protect sc from next-iteration overwrite
  }

  const float inv = 1.0f / ssum;
  pooled[(size_t)n * HDIM + tid]       = a0 * inv;
  pooled[(size_t)n * HDIM + 256 + tid] = a1 * inv;
  pooled[(size_t)n * HDIM + 512 + tid] = a2 * inv;
}

// ---------------- kernel 5: segment mean ----------------
__global__ __launch_bounds__(256) void segmean(const float* __restrict__ pooled,
                                               const void* __restrict__ smap,
                                               const unsigned* __restrict__ flags,
                                               float* __restrict__ out, int N) {
  const int t = blockIdx.x, tid = threadIdx.x;
  const int smap_is_i32 = (flags[1] != 0);
  float a0 = 0.f, a1 = 0.f, a2 = 0.f;
  int cnt = 0;
  for (int i = 0; i < N; ++i) {
    const int s = smap_is_i32 ? ((const int*)smap)[i]
                              : (int)((const long long*)smap)[i];
    if (s == t) {
      a0 += pooled[(size_t)i * HDIM + tid];
      a1 += pooled[(size_t)i * HDIM + 256 + tid];
      a2 += pooled[(size_t)i * HDIM + 512 + tid];
      ++cnt;
    }
  }
  const float inv = 1.0f / (float)(cnt > 0 ? cnt : 1);
  out[(size_t)t * HDIM + tid]       = a0 * inv;
  out[(size_t)t * HDIM + 256 + tid] = a1 * inv;
  out[(size_t)t * HDIM + 512 + tid] = a2 * inv;
}

extern "C" void kernel_launch(void* const* d_in, const int* in_sizes, int n_in,
                              void* d_out, int out_size, void* d_ws, size_t ws_size,
                              hipStream_t stream) {
  const float*    hs     = (const float*)d_in[0];
  const unsigned* mask_w = (const unsigned*)d_in[1];
  const void*     smap   = d_in[2];
  const float*    Wq     = (const float*)d_in[3];
  const float*    bq     = (const float*)d_in[4];
  const float*    Wk     = (const float*)d_in[5];
  // d_in[6] = bk: dead (per-row constant on scores -> softmax-invariant)

  const int N = in_sizes[2];           // 512
  const int L = in_sizes[1] / N;       // 512
  const int H = in_sizes[4];           // 768 (== HDIM)
  const int T = out_size / H;          // 32

  float* meanb  = (float*)d_ws;                 // [N,H]
  float* q      = meanb + (size_t)N * H;        // [N,H]
  float* v      = q     + (size_t)N * H;        // [N,H]
  float* pooled = v     + (size_t)N * H;        // [N,H]
  unsigned* flags = (unsigned*)(pooled + (size_t)N * H);  // [4]
  (void)ws_size; (void)n_in;

  hipMemsetAsync(flags, 0, 16, stream);
  detect_flags<<<64, 256, 0, stream>>>(mask_w, (const unsigned*)smap, flags,
                                       N * L, N);
  mean_kernel<<<N, H / 4, 0, stream>>>(hs, meanb, L);
  gemm_bt<<<dim3(N / 64, H / 64), 512, 0, stream>>>(meanb, Wq, bq, q, N, H, H);
  gemm_bn<<<dim3(N / 64, H / 64), 512, 0, stream>>>(q, Wk, v, N, H, H);
  attnpool<<<N, 256, 0, stream>>>(hs, mask_w, v, flags, pooled, L);
  segmean<<<T, 256, 0, stream>>>(pooled, smap, flags, (float*)d_out, N);
}

// Round 3
// 498.259 us; speedup vs baseline: 1.0651x; 1.0651x over previous
//
#include <hip/hip_runtime.h>
#include <math.h>

#define HDIM 768      // H (hidden) — instance-fixed
#define CHUNK 16      // rows per score/accumulate step (4 waves x 4 rows)
#define LMAX 512      // mask row staged in LDS

__device__ __forceinline__ float dot4(const float4 a, const float4 b) {
  return a.x * b.x + a.y * b.y + a.z * b.z + a.w * b.w;
}
__device__ __forceinline__ void fma4(float4& a, const float s, const float4 b) {
  a.x += s * b.x; a.y += s * b.y; a.z += s * b.z; a.w += s * b.w;
}
__device__ __forceinline__ void scale4(float4& a, const float s) {
  a.x *= s; a.y *= s; a.z *= s; a.w *= s;
}

// ---------------- kernel 0a: zero the flag words ----------------
__global__ void zero_flags(unsigned* flags) {
  if (threadIdx.x < 4) flags[threadIdx.x] = 0u;
}

// ---------------- kernel 0b: input-width detection ----------------
// flags[0] != 0 -> attention_mask is int32-layout (else int64)
// flags[1] != 0 -> sample_map is int32-layout (else int64)
__global__ __launch_bounds__(256) void detect_flags(const unsigned* __restrict__ mask_w,
                                                    const unsigned* __restrict__ smap_w,
                                                    unsigned* __restrict__ flags,
                                                    int mask_words, int smap_words) {
  const int gtid = blockIdx.x * blockDim.x + threadIdx.x;
  const int gsz = gridDim.x * blockDim.x;
  unsigned acc = 0;
  for (int i = gtid; i < mask_words / 2; i += gsz) acc |= mask_w[2 * i + 1];
  if (acc) atomicOr(&flags[0], 1u);
  unsigned acc2 = 0;
  for (int i = gtid; i < smap_words / 2; i += gsz) acc2 |= smap_w[2 * i + 1];
  if (acc2) atomicOr(&flags[1], 1u);
}

// ---------------- kernel 1: mean over L ----------------
__global__ __launch_bounds__(192) void mean_kernel(const float* __restrict__ hs,
                                                   float* __restrict__ meanb, int L) {
  const int n = blockIdx.x;
  const int t = threadIdx.x;  // 0..191
  const float4* row = reinterpret_cast<const float4*>(hs) + (size_t)n * L * (HDIM / 4);
  float ax = 0.f, ay = 0.f, az = 0.f, aw = 0.f;
  int l = 0;
  for (; l + 8 <= L; l += 8) {
    float4 u[8];
#pragma unroll
    for (int i = 0; i < 8; ++i) u[i] = row[(size_t)(l + i) * (HDIM / 4) + t];
#pragma unroll
    for (int i = 0; i < 8; ++i) { ax += u[i].x; ay += u[i].y; az += u[i].z; aw += u[i].w; }
  }
  for (; l < L; ++l) {
    float4 u = row[(size_t)l * (HDIM / 4) + t];
    ax += u.x; ay += u.y; az += u.z; aw += u.w;
  }
  const float inv = 1.0f / (float)L;
  float4 o; o.x = ax * inv; o.y = ay * inv; o.z = az * inv; o.w = aw * inv;
  reinterpret_cast<float4*>(meanb + (size_t)n * HDIM)[t] = o;
}

// ---------------- kernel 2: C[M,Nn] = A[M,K] * B[Nn,K]^T + bias ----------------
// 32x64 tile, 256 threads, 2x4 micro-tile -> 192 blocks at 512x768.
__global__ __launch_bounds__(256) void gemm_bt(const float* __restrict__ A,
                                               const float* __restrict__ B,
                                               const float* __restrict__ bias,
                                               float* __restrict__ C,
                                               int M, int Nn, int K) {
  __shared__ float As[32][17];
  __shared__ float Bs[64][17];
  const int m0 = blockIdx.x * 32, n0 = blockIdx.y * 64;
  const int idx = threadIdx.x;
  const int lc = idx & 15, lr = idx >> 4;   // 0..15
  const int tc = idx & 15, tr = idx >> 4;   // 0..15
  float c[2][4] = {{0.f,0.f,0.f,0.f},{0.f,0.f,0.f,0.f}};
  for (int k0 = 0; k0 < K; k0 += 16) {
    __syncthreads();
    As[lr][lc]      = A[(size_t)(m0 + lr) * K + k0 + lc];
    As[lr + 16][lc] = A[(size_t)(m0 + lr + 16) * K + k0 + lc];
    Bs[lr][lc]      = B[(size_t)(n0 + lr) * K + k0 + lc];
    Bs[lr + 16][lc] = B[(size_t)(n0 + lr + 16) * K + k0 + lc];
    Bs[lr + 32][lc] = B[(size_t)(n0 + lr + 32) * K + k0 + lc];
    Bs[lr + 48][lc] = B[(size_t)(n0 + lr + 48) * K + k0 + lc];
    __syncthreads();
#pragma unroll
    for (int k = 0; k < 16; ++k) {
      const float a0 = As[tr * 2][k], a1 = As[tr * 2 + 1][k];
      const float b0 = Bs[tc * 4][k], b1 = Bs[tc * 4 + 1][k];
      const float b2 = Bs[tc * 4 + 2][k], b3 = Bs[tc * 4 + 3][k];
      c[0][0] += a0 * b0; c[0][1] += a0 * b1; c[0][2] += a0 * b2; c[0][3] += a0 * b3;
      c[1][0] += a1 * b0; c[1][1] += a1 * b1; c[1][2] += a1 * b2; c[1][3] += a1 * b3;
    }
  }
#pragma unroll
  for (int j = 0; j < 4; ++j) {
    const float bv = bias ? bias[n0 + tc * 4 + j] : 0.f;
    C[(size_t)(m0 + tr * 2) * Nn + n0 + tc * 4 + j]     = c[0][j] + bv;
    C[(size_t)(m0 + tr * 2 + 1) * Nn + n0 + tc * 4 + j] = c[1][j] + bv;
  }
}

// ---------------- kernel 3: C[M,Nn] = A[M,K] * B[K,Nn] ----------------
__global__ __launch_bounds__(256) void gemm_bn(const float* __restrict__ A,
                                               const float* __restrict__ B,
                                               float* __restrict__ C,
                                               int M, int Nn, int K) {
  __shared__ float As[32][17];
  __shared__ float Bs[16][65];
  const int m0 = blockIdx.x * 32, n0 = blockIdx.y * 64;
  const int idx = threadIdx.x;
  const int lc = idx & 15, lr = idx >> 4;   // A load, lr 0..15
  const int bc = idx & 63, br = idx >> 6;   // B load, br 0..3
  const int tc = idx & 15, tr = idx >> 4;
  float c[2][4] = {{0.f,0.f,0.f,0.f},{0.f,0.f,0.f,0.f}};
  for (int k0 = 0; k0 < K; k0 += 16) {
    __syncthreads();
    As[lr][lc]      = A[(size_t)(m0 + lr) * K + k0 + lc];
    As[lr + 16][lc] = A[(size_t)(m0 + lr + 16) * K + k0 + lc];
    Bs[br][bc]      = B[(size_t)(k0 + br) * Nn + n0 + bc];
    Bs[br + 4][bc]  = B[(size_t)(k0 + br + 4) * Nn + n0 + bc];
    Bs[br + 8][bc]  = B[(size_t)(k0 + br + 8) * Nn + n0 + bc];
    Bs[br + 12][bc] = B[(size_t)(k0 + br + 12) * Nn + n0 + bc];
    __syncthreads();
#pragma unroll
    for (int k = 0; k < 16; ++k) {
      const float a0 = As[tr * 2][k], a1 = As[tr * 2 + 1][k];
      const float b0 = Bs[k][tc * 4], b1 = Bs[k][tc * 4 + 1];
      const float b2 = Bs[k][tc * 4 + 2], b3 = Bs[k][tc * 4 + 3];
      c[0][0] += a0 * b0; c[0][1] += a0 * b1; c[0][2] += a0 * b2; c[0][3] += a0 * b3;
      c[1][0] += a1 * b0; c[1][1] += a1 * b1; c[1][2] += a1 * b2; c[1][3] += a1 * b3;
    }
  }
#pragma unroll
  for (int j = 0; j < 4; ++j) {
    C[(size_t)(m0 + tr * 2) * Nn + n0 + tc * 4 + j]     = c[0][j];
    C[(size_t)(m0 + tr * 2 + 1) * Nn + n0 + tc * 4 + j] = c[1][j];
  }
}

// ---------------- kernel 4: fused scores + online softmax + weighted pool ----------------
// Each hs row is loaded ONCE into registers (double-buffered prefetch) and used
// for both the score dot-product and the accumulate. Per-wave row-layout
// accumulators; one barrier per 16-row chunk; cross-wave LDS reduce at the end.
__global__ __launch_bounds__(256) void attnpool(const float* __restrict__ hs,
                                                const unsigned* __restrict__ mask_w,
                                                const float* __restrict__ v,
                                                const unsigned* __restrict__ flags,
                                                float* __restrict__ pooled, int L) {
  __shared__ float sc[2][CHUNK];
  __shared__ int   mrow[LMAX];
  __shared__ float red[4][HDIM];   // 12 KB cross-wave reduce
  const int n = blockIdx.x;
  const int tid = threadIdx.x;
  const int w = tid >> 6, lane = tid & 63;

  const int mask_is_i32 = (flags[0] != 0);
  for (int t = tid; t < L; t += 256) {
    const size_t idx = (size_t)n * L + t;
    mrow[t] = (int)(mask_is_i32 ? mask_w[idx] : mask_w[2 * idx]);
  }

  const float4* v4 = reinterpret_cast<const float4*>(v + (size_t)n * HDIM);
  const float4 vf0 = v4[lane], vf1 = v4[64 + lane], vf2 = v4[128 + lane];
  const float4* hs4 = reinterpret_cast<const float4*>(hs) + (size_t)n * L * (HDIM / 4);
  const float scale = 1.0f / sqrtf((float)HDIM);

  float4 A0 = {0,0,0,0}, A1 = {0,0,0,0}, A2 = {0,0,0,0};
  float m = -1e9f, ssum = 0.f;
  float4 xa[4][3], xb[4][3];

  auto prefetch = [&](float4 (&X)[4][3], int c) {
    const float4* rp = hs4 + ((size_t)c * CHUNK + w * 4) * (HDIM / 4);
#pragma unroll
    for (int q = 0; q < 4; ++q) {
      X[q][0] = rp[q * (HDIM / 4) + lane];
      X[q][1] = rp[q * (HDIM / 4) + 64 + lane];
      X[q][2] = rp[q * (HDIM / 4) + 128 + lane];
    }
  };
  auto process = [&](float4 (&X)[4][3], int c) {
#pragma unroll
    for (int q = 0; q < 4; ++q) {
      float p = dot4(X[q][0], vf0) + dot4(X[q][1], vf1) + dot4(X[q][2], vf2);
#pragma unroll
      for (int off = 32; off > 0; off >>= 1) p += __shfl_xor(p, off, 64);
      float s = p * scale;
      if (mrow[c * CHUNK + w * 4 + q] == 0) s = -1e9f;
      if (lane == 0) sc[c & 1][w * 4 + q] = s;
    }
    __syncthreads();  // scores of chunk c visible (sc double-buffered -> only barrier)
    float pp[CHUNK];
    float mc = -3e38f;
#pragma unroll
    for (int r = 0; r < CHUNK; ++r) { pp[r] = sc[c & 1][r]; mc = fmaxf(mc, pp[r]); }
    const float mn = fmaxf(m, mc);
    const float f = __expf(m - mn);
    float psum = 0.f;
#pragma unroll
    for (int r = 0; r < CHUNK; ++r) { pp[r] = __expf(pp[r] - mn); psum += pp[r]; }
    ssum = ssum * f + psum;
    scale4(A0, f); scale4(A1, f); scale4(A2, f);
#pragma unroll
    for (int q = 0; q < 4; ++q) {
      const float wgt = pp[w * 4 + q];
      fma4(A0, wgt, X[q][0]); fma4(A1, wgt, X[q][1]); fma4(A2, wgt, X[q][2]);
    }
    m = mn;
  };

  __syncthreads();  // mrow staged
  prefetch(xa, 0);
  const int nch = L / CHUNK;  // 32 (even)
  for (int c = 0; c < nch; c += 2) {
    prefetch(xb, c + 1);
    process(xa, c);
    if (c + 2 < nch) prefetch(xa, c + 2);
    process(xb, c + 1);
  }

  // cross-wave reduce + normalize
  {
    float* rw = red[w];
    *reinterpret_cast<float4*>(rw + 4 * lane)       = A0;
    *reinterpret_cast<float4*>(rw + 256 + 4 * lane) = A1;
    *reinterpret_cast<float4*>(rw + 512 + 4 * lane) = A2;
  }
  __syncthreads();
  const float inv = 1.0f / ssum;
  const float o0 = red[0][tid] + red[1][tid] + red[2][tid] + red[3][tid];
  const float o1 = red[0][256 + tid] + red[1][256 + tid] + red[2][256 + tid] + red[3][256 + tid];
  const float o2 = red[0][512 + tid] + red[1][512 + tid] + red[2][512 + tid] + red[3][512 + tid];
  pooled[(size_t)n * HDIM + tid]       = o0 * inv;
  pooled[(size_t)n * HDIM + 256 + tid] = o1 * inv;
  pooled[(size_t)n * HDIM + 512 + tid] = o2 * inv;
}

// ---------------- kernel 5: segment mean ----------------
// grid (T, 3): block (t, third) handles 256 output columns of text t.
__global__ __launch_bounds__(256) void segmean(const float* __restrict__ pooled,
                                               const void* __restrict__ smap,
                                               const unsigned* __restrict__ flags,
                                               float* __restrict__ out, int N) {
  const int t = blockIdx.x, tid = threadIdx.x;
  const int col = blockIdx.y * 256 + tid;
  const int smap_is_i32 = (flags[1] != 0);
  float a = 0.f;
  int cnt = 0;
  for (int i = 0; i < N; ++i) {
    const int s = smap_is_i32 ? ((const int*)smap)[i]
                              : (int)((const long long*)smap)[i];
    if (s == t) { a += pooled[(size_t)i * HDIM + col]; ++cnt; }
  }
  out[(size_t)t * HDIM + col] = a / (float)(cnt > 0 ? cnt : 1);
}

extern "C" void kernel_launch(void* const* d_in, const int* in_sizes, int n_in,
                              void* d_out, int out_size, void* d_ws, size_t ws_size,
                              hipStream_t stream) {
  const float*    hs     = (const float*)d_in[0];
  const unsigned* mask_w = (const unsigned*)d_in[1];
  const void*     smap   = d_in[2];
  const float*    Wq     = (const float*)d_in[3];
  const float*    bq     = (const float*)d_in[4];
  const float*    Wk     = (const float*)d_in[5];
  // d_in[6] = bk: dead (per-row constant on scores -> softmax-invariant)

  const int N = in_sizes[2];           // 512
  const int L = in_sizes[1] / N;       // 512
  const int H = in_sizes[4];           // 768 (== HDIM)
  const int T = out_size / H;          // 32

  float* meanb  = (float*)d_ws;                 // [N,H]
  float* q      = meanb + (size_t)N * H;        // [N,H]
  float* v      = q     + (size_t)N * H;        // [N,H]
  float* pooled = v     + (size_t)N * H;        // [N,H]
  unsigned* flags = (unsigned*)(pooled + (size_t)N * H);  // [4]
  (void)ws_size; (void)n_in;

  zero_flags<<<1, 64, 0, stream>>>(flags);
  detect_flags<<<64, 256, 0, stream>>>(mask_w, (const unsigned*)smap, flags,
                                       N * L, N);
  mean_kernel<<<N, H / 4, 0, stream>>>(hs, meanb, L);
  gemm_bt<<<dim3(N / 32, H / 64), 256, 0, stream>>>(meanb, Wq, bq, q, N, H, H);
  gemm_bn<<<dim3(N / 32, H / 64), 256, 0, stream>>>(q, Wk, v, N, H, H);
  attnpool<<<N, 256, 0, stream>>>(hs, mask_w, v, flags, pooled, L);
  segmean<<<dim3(T, 3), 256, 0, stream>>>(pooled, smap, flags, (float*)d_out, N);
}

// Round 4
// 439.124 us; speedup vs baseline: 1.2085x; 1.1347x over previous
//
#include <hip/hip_runtime.h>
#include <math.h>

#define HDIM 768      // H (hidden) — instance-fixed
#define LMAX 512      // mask row staged in LDS

__device__ __forceinline__ float dot4(const float4 a, const float4 b) {
  return a.x * b.x + a.y * b.y + a.z * b.z + a.w * b.w;
}
__device__ __forceinline__ void fma4(float4& a, const float s, const float4 b) {
  a.x += s * b.x; a.y += s * b.y; a.z += s * b.z; a.w += s * b.w;
}
__device__ __forceinline__ void scale4(float4& a, const float s) {
  a.x *= s; a.y *= s; a.z *= s; a.w *= s;
}

// ---------------- kernel 0a: zero the flag words ----------------
__global__ void zero_flags(unsigned* flags) {
  if (threadIdx.x < 4) flags[threadIdx.x] = 0u;
}

// ---------------- kernel 0b: input-width detection ----------------
// flags[0] != 0 -> attention_mask is int32-layout (else int64)
// flags[1] != 0 -> sample_map is int32-layout (else int64)
__global__ __launch_bounds__(256) void detect_flags(const unsigned* __restrict__ mask_w,
                                                    const unsigned* __restrict__ smap_w,
                                                    unsigned* __restrict__ flags,
                                                    int mask_words, int smap_words) {
  const int gtid = blockIdx.x * blockDim.x + threadIdx.x;
  const int gsz = gridDim.x * blockDim.x;
  unsigned acc = 0;
  for (int i = gtid; i < mask_words / 2; i += gsz) acc |= mask_w[2 * i + 1];
  if (acc) atomicOr(&flags[0], 1u);
  unsigned acc2 = 0;
  for (int i = gtid; i < smap_words / 2; i += gsz) acc2 |= smap_w[2 * i + 1];
  if (acc2) atomicOr(&flags[1], 1u);
}

// ---------------- kernel 1: mean over L ----------------
// 384 threads: half h handles rows l%2==h, col-group t (0..191). 6 waves/block.
__global__ __launch_bounds__(384) void mean_kernel(const float* __restrict__ hs,
                                                   float* __restrict__ meanb, int L) {
  __shared__ float4 red2[HDIM / 4];  // 3 KB
  const int n = blockIdx.x;
  const int tid = threadIdx.x;
  const int half = tid / 192, t = tid % 192;
  const float4* row = reinterpret_cast<const float4*>(hs) + (size_t)n * L * (HDIM / 4);
  float ax = 0.f, ay = 0.f, az = 0.f, aw = 0.f;
  int l = half;
  for (; l + 16 <= L; l += 16) {
    float4 u[8];
#pragma unroll
    for (int i = 0; i < 8; ++i) u[i] = row[(size_t)(l + 2 * i) * (HDIM / 4) + t];
#pragma unroll
    for (int i = 0; i < 8; ++i) { ax += u[i].x; ay += u[i].y; az += u[i].z; aw += u[i].w; }
  }
  for (; l < L; l += 2) {
    float4 u = row[(size_t)l * (HDIM / 4) + t];
    ax += u.x; ay += u.y; az += u.z; aw += u.w;
  }
  if (half == 1) { float4 o; o.x = ax; o.y = ay; o.z = az; o.w = aw; red2[t] = o; }
  __syncthreads();
  if (half == 0) {
    const float inv = 1.0f / (float)L;
    const float4 r = red2[t];
    float4 o;
    o.x = (ax + r.x) * inv; o.y = (ay + r.y) * inv;
    o.z = (az + r.z) * inv; o.w = (aw + r.w) * inv;
    reinterpret_cast<float4*>(meanb + (size_t)n * HDIM)[t] = o;
  }
}

// ---------------- kernel 2: C[M,Nn] = A[M,K] * B[Nn,K]^T + bias ----------------
__global__ __launch_bounds__(256) void gemm_bt(const float* __restrict__ A,
                                               const float* __restrict__ B,
                                               const float* __restrict__ bias,
                                               float* __restrict__ C,
                                               int M, int Nn, int K) {
  __shared__ float As[32][17];
  __shared__ float Bs[64][17];
  const int m0 = blockIdx.x * 32, n0 = blockIdx.y * 64;
  const int idx = threadIdx.x;
  const int lc = idx & 15, lr = idx >> 4;
  const int tc = idx & 15, tr = idx >> 4;
  float c[2][4] = {{0.f,0.f,0.f,0.f},{0.f,0.f,0.f,0.f}};
  for (int k0 = 0; k0 < K; k0 += 16) {
    __syncthreads();
    As[lr][lc]      = A[(size_t)(m0 + lr) * K + k0 + lc];
    As[lr + 16][lc] = A[(size_t)(m0 + lr + 16) * K + k0 + lc];
    Bs[lr][lc]      = B[(size_t)(n0 + lr) * K + k0 + lc];
    Bs[lr + 16][lc] = B[(size_t)(n0 + lr + 16) * K + k0 + lc];
    Bs[lr + 32][lc] = B[(size_t)(n0 + lr + 32) * K + k0 + lc];
    Bs[lr + 48][lc] = B[(size_t)(n0 + lr + 48) * K + k0 + lc];
    __syncthreads();
#pragma unroll
    for (int k = 0; k < 16; ++k) {
      const float a0 = As[tr * 2][k], a1 = As[tr * 2 + 1][k];
      const float b0 = Bs[tc * 4][k], b1 = Bs[tc * 4 + 1][k];
      const float b2 = Bs[tc * 4 + 2][k], b3 = Bs[tc * 4 + 3][k];
      c[0][0] += a0 * b0; c[0][1] += a0 * b1; c[0][2] += a0 * b2; c[0][3] += a0 * b3;
      c[1][0] += a1 * b0; c[1][1] += a1 * b1; c[1][2] += a1 * b2; c[1][3] += a1 * b3;
    }
  }
#pragma unroll
  for (int j = 0; j < 4; ++j) {
    const float bv = bias ? bias[n0 + tc * 4 + j] : 0.f;
    C[(size_t)(m0 + tr * 2) * Nn + n0 + tc * 4 + j]     = c[0][j] + bv;
    C[(size_t)(m0 + tr * 2 + 1) * Nn + n0 + tc * 4 + j] = c[1][j] + bv;
  }
}

// ---------------- kernel 3: C[M,Nn] = A[M,K] * B[K,Nn] ----------------
__global__ __launch_bounds__(256) void gemm_bn(const float* __restrict__ A,
                                               const float* __restrict__ B,
                                               float* __restrict__ C,
                                               int M, int Nn, int K) {
  __shared__ float As[32][17];
  __shared__ float Bs[16][65];
  const int m0 = blockIdx.x * 32, n0 = blockIdx.y * 64;
  const int idx = threadIdx.x;
  const int lc = idx & 15, lr = idx >> 4;
  const int bc = idx & 63, br = idx >> 6;
  const int tc = idx & 15, tr = idx >> 4;
  float c[2][4] = {{0.f,0.f,0.f,0.f},{0.f,0.f,0.f,0.f}};
  for (int k0 = 0; k0 < K; k0 += 16) {
    __syncthreads();
    As[lr][lc]      = A[(size_t)(m0 + lr) * K + k0 + lc];
    As[lr + 16][lc] = A[(size_t)(m0 + lr + 16) * K + k0 + lc];
    Bs[br][bc]      = B[(size_t)(k0 + br) * Nn + n0 + bc];
    Bs[br + 4][bc]  = B[(size_t)(k0 + br + 4) * Nn + n0 + bc];
    Bs[br + 8][bc]  = B[(size_t)(k0 + br + 8) * Nn + n0 + bc];
    Bs[br + 12][bc] = B[(size_t)(k0 + br + 12) * Nn + n0 + bc];
    __syncthreads();
#pragma unroll
    for (int k = 0; k < 16; ++k) {
      const float a0 = As[tr * 2][k], a1 = As[tr * 2 + 1][k];
      const float b0 = Bs[k][tc * 4], b1 = Bs[k][tc * 4 + 1];
      const float b2 = Bs[k][tc * 4 + 2], b3 = Bs[k][tc * 4 + 3];
      c[0][0] += a0 * b0; c[0][1] += a0 * b1; c[0][2] += a0 * b2; c[0][3] += a0 * b3;
      c[1][0] += a1 * b0; c[1][1] += a1 * b1; c[1][2] += a1 * b2; c[1][3] += a1 * b3;
    }
  }
#pragma unroll
  for (int j = 0; j < 4; ++j) {
    C[(size_t)(m0 + tr * 2) * Nn + n0 + tc * 4 + j]     = c[0][j];
    C[(size_t)(m0 + tr * 2 + 1) * Nn + n0 + tc * 4 + j] = c[1][j];
  }
}

// ---------------- kernel 4: fused scores + online softmax + weighted pool ----------------
// Barrier-free main loop: each wave owns a contiguous L/4-row strip with a
// wave-local online softmax (m, ssum, acc all in registers; scores via
// __shfl_xor). Split-softmax merge across the 4 waves ONCE at the end.
// n reversed so the tail of the mean pass's stream is still L3-resident.
__global__ __launch_bounds__(256) void attnpool(const float* __restrict__ hs,
                                                const unsigned* __restrict__ mask_w,
                                                const float* __restrict__ v,
                                                const unsigned* __restrict__ flags,
                                                float* __restrict__ pooled, int L) {
  __shared__ int   mrow[LMAX];
  __shared__ float red[4][HDIM];   // 12 KB cross-wave accumulator merge
  __shared__ float mw[4], sw[4];
  const int n = gridDim.x - 1 - blockIdx.x;  // reversed for L3 reuse
  const int tid = threadIdx.x;
  const int w = tid >> 6, lane = tid & 63;

  const int mask_is_i32 = (flags[0] != 0);
  for (int t = tid; t < L; t += 256) {
    const size_t idx = (size_t)n * L + t;
    mrow[t] = (int)(mask_is_i32 ? mask_w[idx] : mask_w[2 * idx]);
  }

  const float4* v4 = reinterpret_cast<const float4*>(v + (size_t)n * HDIM);
  const float4 vf0 = v4[lane], vf1 = v4[64 + lane], vf2 = v4[128 + lane];
  const float4* hs4 = reinterpret_cast<const float4*>(hs) + (size_t)n * L * (HDIM / 4);
  const float scale = 1.0f / sqrtf((float)HDIM);

  const int rpw = L / 4;           // rows per wave (128)
  const int r0 = w * rpw;
  float4 A0 = {0,0,0,0}, A1 = {0,0,0,0}, A2 = {0,0,0,0};
  float m = -3.0e38f, ssum = 0.f;
  float4 xa[4][3], xb[4][3];

  auto loadg = [&](float4 (&X)[4][3], int g) {
    const float4* rp = hs4 + (size_t)(r0 + g * 4) * (HDIM / 4);
#pragma unroll
    for (int q = 0; q < 4; ++q) {
      X[q][0] = rp[q * (HDIM / 4) + lane];
      X[q][1] = rp[q * (HDIM / 4) + 64 + lane];
      X[q][2] = rp[q * (HDIM / 4) + 128 + lane];
    }
  };
  auto procg = [&](float4 (&X)[4][3], int g) {
    float s[4];
#pragma unroll
    for (int q = 0; q < 4; ++q) {
      float p = dot4(X[q][0], vf0) + dot4(X[q][1], vf1) + dot4(X[q][2], vf2);
#pragma unroll
      for (int off = 32; off > 0; off >>= 1) p += __shfl_xor(p, off, 64);
      s[q] = (mrow[r0 + g * 4 + q] == 0) ? -1e9f : p * scale;
    }
    const float mc = fmaxf(fmaxf(s[0], s[1]), fmaxf(s[2], s[3]));
    if (mc > m) {  // wave-uniform branch; defer rescale until max actually grows
      const float f = __expf(m - mc);
      ssum *= f; scale4(A0, f); scale4(A1, f); scale4(A2, f);
      m = mc;
    }
#pragma unroll
    for (int q = 0; q < 4; ++q) {
      const float pq = __expf(s[q] - m);
      ssum += pq;
      fma4(A0, pq, X[q][0]); fma4(A1, pq, X[q][1]); fma4(A2, pq, X[q][2]);
    }
  };

  __syncthreads();  // mrow staged
  loadg(xa, 0);
  const int ng = rpw / 4;  // 32 (even)
  for (int g = 0; g < ng; g += 2) {
    loadg(xb, g + 1);
    procg(xa, g);
    if (g + 2 < ng) loadg(xa, g + 2);
    procg(xb, g + 1);
  }

  // ---- split-softmax merge across waves (single barrier) ----
  if (lane == 0) { mw[w] = m; sw[w] = ssum; }
  {
    float* rw = red[w];
    *reinterpret_cast<float4*>(rw + 4 * lane)       = A0;
    *reinterpret_cast<float4*>(rw + 256 + 4 * lane) = A1;
    *reinterpret_cast<float4*>(rw + 512 + 4 * lane) = A2;
  }
  __syncthreads();
  const float M = fmaxf(fmaxf(mw[0], mw[1]), fmaxf(mw[2], mw[3]));
  const float f0 = __expf(mw[0] - M), f1 = __expf(mw[1] - M);
  const float f2 = __expf(mw[2] - M), f3 = __expf(mw[3] - M);
  const float S = sw[0] * f0 + sw[1] * f1 + sw[2] * f2 + sw[3] * f3;
  const float inv = 1.0f / S;
#pragma unroll
  for (int part = 0; part < 3; ++part) {
    const int col = part * 256 + tid;
    const float o = red[0][col] * f0 + red[1][col] * f1 + red[2][col] * f2 + red[3][col] * f3;
    pooled[(size_t)n * HDIM + col] = o * inv;
  }
}

// ---------------- kernel 5: segment mean ----------------
__global__ __launch_bounds__(256) void segmean(const float* __restrict__ pooled,
                                               const void* __restrict__ smap,
                                               const unsigned* __restrict__ flags,
                                               float* __restrict__ out, int N) {
  const int t = blockIdx.x, tid = threadIdx.x;
  const int col = blockIdx.y * 256 + tid;
  const int smap_is_i32 = (flags[1] != 0);
  float a = 0.f;
  int cnt = 0;
  for (int i = 0; i < N; ++i) {
    const int s = smap_is_i32 ? ((const int*)smap)[i]
                              : (int)((const long long*)smap)[i];
    if (s == t) { a += pooled[(size_t)i * HDIM + col]; ++cnt; }
  }
  out[(size_t)t * HDIM + col] = a / (float)(cnt > 0 ? cnt : 1);
}

extern "C" void kernel_launch(void* const* d_in, const int* in_sizes, int n_in,
                              void* d_out, int out_size, void* d_ws, size_t ws_size,
                              hipStream_t stream) {
  const float*    hs     = (const float*)d_in[0];
  const unsigned* mask_w = (const unsigned*)d_in[1];
  const void*     smap   = d_in[2];
  const float*    Wq     = (const float*)d_in[3];
  const float*    bq     = (const float*)d_in[4];
  const float*    Wk     = (const float*)d_in[5];
  // d_in[6] = bk: dead (per-row constant on scores -> softmax-invariant)

  const int N = in_sizes[2];           // 512
  const int L = in_sizes[1] / N;       // 512
  const int H = in_sizes[4];           // 768 (== HDIM)
  const int T = out_size / H;          // 32

  float* meanb  = (float*)d_ws;                 // [N,H]
  float* q      = meanb + (size_t)N * H;        // [N,H]
  float* v      = q     + (size_t)N * H;        // [N,H]
  float* pooled = v     + (size_t)N * H;        // [N,H]
  unsigned* flags = (unsigned*)(pooled + (size_t)N * H);  // [4]
  (void)ws_size; (void)n_in;

  zero_flags<<<1, 64, 0, stream>>>(flags);
  detect_flags<<<64, 256, 0, stream>>>(mask_w, (const unsigned*)smap, flags,
                                       N * L, N);
  mean_kernel<<<N, 384, 0, stream>>>(hs, meanb, L);
  gemm_bt<<<dim3(N / 32, H / 64), 256, 0, stream>>>(meanb, Wq, bq, q, N, H, H);
  gemm_bn<<<dim3(N / 32, H / 64), 256, 0, stream>>>(q, Wk, v, N, H, H);
  attnpool<<<N, 256, 0, stream>>>(hs, mask_w, v, flags, pooled, L);
  segmean<<<dim3(T, 3), 256, 0, stream>>>(pooled, smap, flags, (float*)d_out, N);
}